// Round 7
// baseline (210.973 us; speedup 1.0000x reference)
//
#include <hip/hip_runtime.h>
#include <hip/hip_bf16.h>
#include <math.h>

#define G_GENES 2000
#define C_CELLS 128
#define H_DIM   256
#define CE_DIM  64
#define LDAe    260   // x1t row stride (bf16 elems): 130 dw = 2 mod 32 -> conflict-free

typedef __attribute__((ext_vector_type(8))) short short8;
typedef __attribute__((ext_vector_type(4))) float floatx4;

__device__ __forceinline__ float eluf(float x) {
    float e = __expf(x) - 1.0f;
    return x > 0.0f ? x : e;
}
__device__ __forceinline__ unsigned short f2bf(float v) {
    unsigned u = __float_as_uint(v);
    u += 0x7FFF + ((u >> 16) & 1);       // RNE
    return (unsigned short)(u >> 16);
}
__device__ __forceinline__ unsigned pk2(float a, float b) {   // v_cvt_pk_bf16_f32
    __hip_bfloat162 h2 = __float22bfloat162_rn(make_float2(a, b));
    unsigned r; __builtin_memcpy(&r, &h2, 4); return r;
}
__device__ __forceinline__ float bflo(unsigned u) { return __uint_as_float(u << 16); }
__device__ __forceinline__ float bfhi(unsigned u) { return __uint_as_float(u & 0xffff0000u); }
union U8 { unsigned u[4]; short8 s; uint4 v; };

// ---------------------------------------------------------------------------
// K_prep: 660 blocks x 512 threads, four roles (R17: k_fin fused in):
//  [0,128):   FULL ce pipeline for cell c = b (replaces split-K hidpart +
//             k_fin): stage ctrl row -> 8-way split-K hid -> elu -> ce GEMV
//             -> Atc GEMV -> Atcbf bf16. No hidpart round-trip, one fewer
//             kernel launch.
//  [128,144): w2abt[n][k] = bf16(g_w2[k][n]), k<256  (MFMA B operand)
//  [144,160): w2bb[h][j]  = bf16(g_w2[256+h][j])     (q-phase weights)
//  [160,660): Bvg[g][h] per-gene bias row (4 genes/block)
// ---------------------------------------------------------------------------
__global__ __launch_bounds__(512) void k_prep(
    const float* __restrict__ ctrl, const float* __restrict__ ce_w1,
    const float* __restrict__ ce_b1, const float* __restrict__ ce_w2,
    const float* __restrict__ ce_b2, const float* __restrict__ g_w1,
    const float* __restrict__ g_b1, const float* __restrict__ shiftv,
    const int* __restrict__ gidx, const float* __restrict__ gtab,
    const float* __restrict__ g_w2,
    unsigned short* __restrict__ Atcbf, unsigned short* __restrict__ w2abt,
    unsigned short* __restrict__ w2bb, float* __restrict__ Bvg)
{
    const int b = blockIdx.x;
    const int t = threadIdx.x;

    if (b < C_CELLS) {
        // ---- fused ce pipeline, one block per cell ----
        __shared__ float cr[G_GENES];        // 8000 B: ctrl row
        __shared__ float hidp[8][H_DIM];     // 8192 B: split-K partials
        __shared__ float hid[H_DIM];
        __shared__ float celp[4][CE_DIM];
        __shared__ float cel[CE_DIM];
        const int c = b;

        #pragma unroll
        for (int p = 0; p < 4; ++p) {
            const int i = p * 512 + t;
            if (i < G_GENES) cr[i] = ctrl[(size_t)c * G_GENES + i];
        }
        __syncthreads();

        {   // hid partials: wave ks owns k in [ks*250, ks*250+250)
            const int ks = t >> 6;              // 0..7 (wave-uniform)
            const int h0 = (t & 63) * 4;
            float4 s = {0.f, 0.f, 0.f, 0.f};
            const float* wb = ce_w1 + (size_t)(ks * 250) * H_DIM + h0;
            const float* cp = cr + ks * 250;
            #pragma unroll 5
            for (int k = 0; k < 250; ++k) {
                const float crv = cp[k];                       // LDS broadcast
                const float4 wv = *(const float4*)(wb + (size_t)k * H_DIM);
                s.x = fmaf(crv, wv.x, s.x);
                s.y = fmaf(crv, wv.y, s.y);
                s.z = fmaf(crv, wv.z, s.z);
                s.w = fmaf(crv, wv.w, s.w);
            }
            *(float4*)&hidp[ks][h0] = s;
        }
        __syncthreads();

        if (t < H_DIM) {
            float hv = ce_b1[t];
            #pragma unroll
            for (int ks = 0; ks < 8; ++ks) hv += hidp[ks][t];
            hid[t] = eluf(hv);
        }
        __syncthreads();

        if (t < H_DIM) {   // celp: quarter-split GEMV (k_fin scheme)
            const int e = t & 63, q4 = t >> 6;
            float cpv = 0.f;
            #pragma unroll 8
            for (int hh = 0; hh < 64; ++hh)
                cpv = fmaf(hid[q4 * 64 + hh],
                           ce_w2[(size_t)(q4 * 64 + hh) * CE_DIM + e], cpv);
            celp[q4][e] = cpv;
        }
        __syncthreads();
        if (t < CE_DIM)
            cel[t] = ce_b2[t] + celp[0][t] + celp[1][t] + celp[2][t] + celp[3][t];
        __syncthreads();

        if (t < H_DIM) {   // Atc GEMV + bf16 store
            float a = 0.f;
            #pragma unroll 8
            for (int e = 0; e < CE_DIM; ++e)
                a = fmaf(cel[e], g_w1[(size_t)(1 + e) * H_DIM + t], a);
            Atcbf[(size_t)c * H_DIM + t] = f2bf(a);
        }
    } else if (b < 144) {
        const int n  = (b - 128) * 16 + (t >> 5);
        const int k0 = (t & 31) * 8;
        float v[8];
        #pragma unroll
        for (int j = 0; j < 8; ++j) v[j] = g_w2[(size_t)(k0 + j) * H_DIM + n];
        U8 u;
        u.u[0] = pk2(v[0], v[1]); u.u[1] = pk2(v[2], v[3]);
        u.u[2] = pk2(v[4], v[5]); u.u[3] = pk2(v[6], v[7]);
        *(uint4*)&w2abt[(size_t)n * H_DIM + k0] = u.v;
    } else if (b < 160) {
        const int hr = (b - 144) * 16 + (t >> 5);
        const int j0 = (t & 31) * 8;
        const float* src = g_w2 + (size_t)(H_DIM + hr) * H_DIM + j0;
        float4 f0 = *(const float4*)src;
        float4 f1 = *(const float4*)(src + 4);
        U8 u;
        u.u[0] = pk2(f0.x, f0.y); u.u[1] = pk2(f0.z, f0.w);
        u.u[2] = pk2(f1.x, f1.y); u.u[3] = pk2(f1.z, f1.w);
        *(uint4*)&w2bb[(size_t)hr * H_DIM + j0] = u.v;
    } else {
        const int gq = b - 160;               // 0..499
        const int half = t >> 8;              // 0/1
        const int h = t & 255;
        const int gA = gq * 4 + half * 2;
        const int gB = gA + 1;
        const int iA = gidx[gA];
        const int iB = gidx[gB];

        const float b1   = g_b1[h];
        const float w129 = g_w1[(size_t)129 * H_DIM + h];
        const float w130 = g_w1[(size_t)130 * H_DIM + h];
        float bvA = b1 + 128.0f * w130 + shiftv[iA] * w129;
        float bvB = b1 + 128.0f * w130 + shiftv[iB] * w129;
        #pragma unroll 8
        for (int e = 0; e < CE_DIM; ++e) {
            const float wv = g_w1[(size_t)(65 + e) * H_DIM + h];
            bvA = fmaf(gtab[(size_t)iA * CE_DIM + e], wv, bvA);
            bvB = fmaf(gtab[(size_t)iB * CE_DIM + e], wv, bvB);
        }
        Bvg[(size_t)gA * H_DIM + h] = bvA;
        Bvg[(size_t)gB * H_DIM + h] = bvB;
    }
}

// ---------------------------------------------------------------------------
// K_main: R16 form, FROZEN (equal-best, 111.3 us). Phase order is load-
// bearing (R15); barriers are free (R16); NOTHING may add VMEM pressure near
// the MFMA loop: 64 VGPR + 64 AGPR is exactly the 128-reg/4-wave boundary
// (R11/R12/R14 all spilled). Occupancy is register-capped at 16 waves/CU.
// ---------------------------------------------------------------------------
__global__ __launch_bounds__(512, 4) void k_main(
    const float* __restrict__ ctrl, const int* __restrict__ gidx,
    const float* __restrict__ g_w1, const float* __restrict__ g_b2,
    const float* __restrict__ g_w3, const unsigned short* __restrict__ Atcbf,
    const float* __restrict__ Bvg, const unsigned short* __restrict__ w2abt,
    const unsigned short* __restrict__ w2bb, float* __restrict__ out)
{
    __shared__ __align__(16) unsigned short x1t[C_CELLS * LDAe];  // 66560 B
    __shared__ __align__(16) float scratch[8 * 258];              // pp -> red2
    __shared__ float pvec[H_DIM];
    __shared__ float qa[H_DIM];
    __shared__ float qb[H_DIM];
    __shared__ float b2l[H_DIM];
    __shared__ float w3v[H_DIM];

    const int g = blockIdx.x;
    const int t = threadIdx.x;
    const int idx = gidx[g];

    const int lane = t & 63;
    const int w    = t >> 6;
    const int quad = lane >> 4;
    const int nlo  = lane & 15;
    const int wm   = w >> 2;
    const int wn   = w & 3;

    // ---- prefetches (all independent) ----
    const int ho = t & 31, cgrp = t >> 5;
    const int h0 = ho * 8;
    uint4 A[8];                    // 8 rows x 8 bf16 Atc values (32 VGPRs)
    #pragma unroll
    for (int i = 0; i < 8; ++i)
        A[i] = *(const uint4*)(Atcbf + (size_t)(cgrp * 8 + i) * H_DIM + h0);
    float4 bv0 = *(const float4*)(Bvg + (size_t)g * H_DIM + h0);
    float4 bv1 = *(const float4*)(Bvg + (size_t)g * H_DIM + h0 + 4);
    float4 wv0 = *(const float4*)(g_w1 + h0);
    float4 wv1 = *(const float4*)(g_w1 + h0 + 4);

    const unsigned short* bbase = w2abt + (size_t)(wn * 64 + nlo) * H_DIM + quad * 8;
    short8 bcur[4];
    #pragma unroll
    for (int nt = 0; nt < 4; ++nt)
        bcur[nt] = *(const short8*)(bbase + (size_t)nt * 16 * H_DIM);

    // ctrl column values for this cgrp: lanes 0-7 of each half-wave load,
    // consumers pick them up via __shfl (no cc[] LDS, no B0).
    float ccl = 0.f;
    if ((lane & 31) < 8)
        ccl = ctrl[(size_t)(cgrp * 8 + (lane & 31)) * G_GENES + idx];

    if (t < H_DIM) {
        w3v[t] = g_w3[t];      // read after B3 only -> B1 covers visibility
        b2l[t] = g_b2[t];
    }

    {   // ---- x1 build (+ register p-partials) ----
        float s[8];
        #pragma unroll
        for (int j = 0; j < 8; ++j) s[j] = 0.f;
        #pragma unroll
        for (int i = 0; i < 8; ++i) {
            const int c = cgrp * 8 + i;
            const float ccv = __shfl(ccl, (lane & 32) + i);
            float v0 = eluf(fmaf(ccv, wv0.x, bflo(A[i].x) + bv0.x));
            float v1 = eluf(fmaf(ccv, wv0.y, bfhi(A[i].x) + bv0.y));
            float v2 = eluf(fmaf(ccv, wv0.z, bflo(A[i].y) + bv0.z));
            float v3 = eluf(fmaf(ccv, wv0.w, bfhi(A[i].y) + bv0.w));
            float v4 = eluf(fmaf(ccv, wv1.x, bflo(A[i].z) + bv1.x));
            float v5 = eluf(fmaf(ccv, wv1.y, bfhi(A[i].z) + bv1.y));
            float v6 = eluf(fmaf(ccv, wv1.z, bflo(A[i].w) + bv1.z));
            float v7 = eluf(fmaf(ccv, wv1.w, bfhi(A[i].w) + bv1.w));
            s[0] += v0; s[1] += v1; s[2] += v2; s[3] += v3;
            s[4] += v4; s[5] += v5; s[6] += v6; s[7] += v7;
            uint4 pk;
            pk.x = pk2(v0, v1); pk.y = pk2(v2, v3);
            pk.z = pk2(v4, v5); pk.w = pk2(v6, v7);
            *(uint4*)&x1t[c * LDAe + h0] = pk;
        }
        #pragma unroll
        for (int j = 0; j < 8; ++j) s[j] += __shfl_xor(s[j], 32);
        if (lane < 32) {
            float4 p0 = {s[0], s[1], s[2], s[3]};
            float4 p1 = {s[4], s[5], s[6], s[7]};
            *(float4*)&scratch[w * 258 + h0] = p0;
            *(float4*)&scratch[w * 258 + h0 + 4] = p1;
        }
    }
    __syncthreads();   // B1: x1t + pp complete

    // ---- MFMA: 4mt x 4nt, K=256 in 8 steps, B-frags double-buffered ----
    floatx4 acc[4][4];
    #pragma unroll
    for (int mt = 0; mt < 4; ++mt)
        #pragma unroll
        for (int nt = 0; nt < 4; ++nt)
            acc[mt][nt] = (floatx4){0.f, 0.f, 0.f, 0.f};

    const unsigned short* abase = &x1t[(wm * 64 + nlo) * LDAe + quad * 8];

    #pragma unroll
    for (int kt = 0; kt < 8; ++kt) {
        short8 af[4];
        #pragma unroll
        for (int mt = 0; mt < 4; ++mt)
            af[mt] = *(const short8*)(abase + mt * 16 * LDAe + kt * 32);
        short8 bnx[4];
        if (kt < 7) {
            #pragma unroll
            for (int nt = 0; nt < 4; ++nt)
                bnx[nt] = *(const short8*)(bbase + (size_t)nt * 16 * H_DIM + (kt + 1) * 32);
        }
        #pragma unroll
        for (int nt = 0; nt < 4; ++nt)
            #pragma unroll
            for (int mt = 0; mt < 4; ++mt)
                acc[mt][nt] = __builtin_amdgcn_mfma_f32_16x16x32_bf16(af[mt], bcur[nt], acc[mt][nt], 0, 0, 0);
        if (kt < 7) {
            #pragma unroll
            for (int nt = 0; nt < 4; ++nt) bcur[nt] = bnx[nt];
        }
    }

    // ---- p-reduce into pvec ----
    if (t < H_DIM) {
        float ps = 0.f;
        #pragma unroll
        for (int w2 = 0; w2 < 8; ++w2) ps += scratch[w2 * 258 + t];
        pvec[t] = ps * (1.0f / 128.0f);
    }
    __syncthreads();   // B2: pvec ready

    // ---- q halves: qa (h<128), qb (h>=128); scalar loads (reg-safe) ----
    {
        const int j = t & 255, hf = t >> 8;
        const unsigned short* wp = w2bb + (size_t)(hf * 128) * H_DIM + j;
        const float* pv = pvec + hf * 128;
        float q0 = 0.f, q1 = 0.f, q2 = 0.f, q3 = 0.f;
        #pragma unroll 8
        for (int h = 0; h < 128; h += 4) {
            q0 = fmaf(pv[h + 0], bflo((unsigned)wp[(size_t)(h + 0) * H_DIM] << 16), q0);
            q1 = fmaf(pv[h + 1], bflo((unsigned)wp[(size_t)(h + 1) * H_DIM] << 16), q1);
            q2 = fmaf(pv[h + 2], bflo((unsigned)wp[(size_t)(h + 2) * H_DIM] << 16), q2);
            q3 = fmaf(pv[h + 3], bflo((unsigned)wp[(size_t)(h + 3) * H_DIM] << 16), q3);
        }
        const float qp = (q0 + q1) + (q2 + q3);
        if (hf) qb[j] = qp; else qa[j] = qp;
    }
    __syncthreads();   // B3: qa/qb ready

    // ---- epilogue: logit partials (C/D: col=lane&15, row=quad*4+reg) ----
    float* red2 = scratch;
    float qj[4], w3j[4];
    #pragma unroll
    for (int nt = 0; nt < 4; ++nt) {
        const int j = wn * 64 + nt * 16 + nlo;
        qj[nt] = qa[j] + qb[j] + b2l[j];
        w3j[nt] = w3v[j];
    }
    #pragma unroll
    for (int mt = 0; mt < 4; ++mt) {
        #pragma unroll
        for (int reg = 0; reg < 4; ++reg) {
            float part = 0.f;
            #pragma unroll
            for (int nt = 0; nt < 4; ++nt)
                part = fmaf(eluf(acc[mt][nt][reg] + qj[nt]), w3j[nt], part);
            part += __shfl_xor(part, 1);
            part += __shfl_xor(part, 2);
            part += __shfl_xor(part, 4);
            part += __shfl_xor(part, 8);
            if (nlo == 0)
                red2[(wm * 64 + mt * 16 + quad * 4 + reg) * 5 + wn] = part;
        }
    }
    __syncthreads();   // B4: red2 complete

    // ---- softmax: wave 0 only, 2 cells/lane ----
    if (t < 64) {
        const float s0 = red2[t * 5 + 0] + red2[t * 5 + 1]
                       + red2[t * 5 + 2] + red2[t * 5 + 3];
        const float s1 = red2[(t + 64) * 5 + 0] + red2[(t + 64) * 5 + 1]
                       + red2[(t + 64) * 5 + 2] + red2[(t + 64) * 5 + 3];
        const float e0 = __expf(fminf(s0, 80.f));
        const float e1 = __expf(fminf(s1, 80.f));
        float S = e0 + e1;
        #pragma unroll
        for (int off = 1; off < 64; off <<= 1) S += __shfl_xor(S, off);
        const float inv = 1.0f / S;
        out[(size_t)t * G_GENES + g] = e0 * inv;
        out[(size_t)(t + 64) * G_GENES + g] = e1 * inv;
    }
}

// ---------------------------------------------------------------------------
extern "C" void kernel_launch(void* const* d_in, const int* in_sizes, int n_in,
                              void* d_out, int out_size, void* d_ws, size_t ws_size,
                              hipStream_t stream) {
    const float* ctrl   = (const float*)d_in[0];
    const float* shiftv = (const float*)d_in[1];
    const int*   gidx   = (const int*)d_in[2];
    const float* ce_w1  = (const float*)d_in[3];
    const float* ce_b1  = (const float*)d_in[4];
    const float* ce_w2  = (const float*)d_in[5];
    const float* ce_b2  = (const float*)d_in[6];
    const float* gtab   = (const float*)d_in[7];
    const float* g_w1   = (const float*)d_in[8];
    const float* g_b1   = (const float*)d_in[9];
    const float* g_w2   = (const float*)d_in[10];
    const float* g_b2   = (const float*)d_in[11];
    const float* g_w3   = (const float*)d_in[12];
    // g_b3 and the p2@w3b term are per-gene constants: cancel in softmax.

    // workspace: Atcbf 128K | w2abt 128K | w2bb 128K | Bvg 2M
    char* ws = (char*)d_ws;
    unsigned short* Atcbf = (unsigned short*)(ws);
    unsigned short* w2abt = (unsigned short*)(ws + 128 * 1024);
    unsigned short* w2bb  = (unsigned short*)(ws + 256 * 1024);
    float* Bvg            = (float*)(ws + 384 * 1024);
    float* out            = (float*)d_out;

    k_prep<<<660, 512, 0, stream>>>(
        ctrl, ce_w1, ce_b1, ce_w2, ce_b2, g_w1, g_b1, shiftv, gidx, gtab, g_w2,
        Atcbf, w2abt, w2bb, Bvg);
    k_main<<<G_GENES, 512, 0, stream>>>(ctrl, gidx, g_w1, g_b2, g_w3,
                                        Atcbf, Bvg, w2abt, w2bb, out);
}

// Round 8
// 203.574 us; speedup vs baseline: 1.0363x; 1.0363x over previous
//
#include <hip/hip_runtime.h>
#include <hip/hip_bf16.h>
#include <math.h>

#define G_GENES 2000
#define C_CELLS 128
#define H_DIM   256
#define CE_DIM  64
#define LDAe    260   // x1t row stride (bf16 elems): 130 dw = 2 mod 32 -> conflict-free

typedef __attribute__((ext_vector_type(8))) short short8;
typedef __attribute__((ext_vector_type(4))) float floatx4;

__device__ __forceinline__ float eluf(float x) {
    float e = __expf(x) - 1.0f;
    return x > 0.0f ? x : e;
}
__device__ __forceinline__ unsigned short f2bf(float v) {
    unsigned u = __float_as_uint(v);
    u += 0x7FFF + ((u >> 16) & 1);       // RNE
    return (unsigned short)(u >> 16);
}
__device__ __forceinline__ unsigned pk2(float a, float b) {   // v_cvt_pk_bf16_f32
    __hip_bfloat162 h2 = __float22bfloat162_rn(make_float2(a, b));
    unsigned r; __builtin_memcpy(&r, &h2, 4); return r;
}
__device__ __forceinline__ float bflo(unsigned u) { return __uint_as_float(u << 16); }
__device__ __forceinline__ float bfhi(unsigned u) { return __uint_as_float(u & 0xffff0000u); }
union U8 { unsigned u[4]; short8 s; uint4 v; };

// ---------------------------------------------------------------------------
// K_g1: 788 blocks x 512 threads, four roles (R13 structure — measured best):
//  [0,256):    fp32 split-K hid partials (1 cell x 4 h, float4 w-loads)
//  [256,272):  w2abt[n][k] = bf16(g_w2[k][n]), k<256  (MFMA B operand)
//  [272,288):  w2bb[h][j]  = bf16(g_w2[256+h][j])     (q-phase weights)
//  [288,788):  Bvg[g][h] per-gene bias row (4 genes/block)
// R17 lesson: fusing k_fin in (one block/cell, 250-deep chain) was SLOWER;
// keep the split-K + k_fin split.
// ---------------------------------------------------------------------------
__global__ __launch_bounds__(512) void k_g1(
    const float* __restrict__ ctrl, const float* __restrict__ ce_w1,
    const float* __restrict__ g_w1, const float* __restrict__ g_b1,
    const float* __restrict__ shiftv, const int* __restrict__ gidx,
    const float* __restrict__ gtab, const float* __restrict__ g_w2,
    float* __restrict__ hidpart, unsigned short* __restrict__ w2abt,
    unsigned short* __restrict__ w2bb, float* __restrict__ Bvg)
{
    const int b = blockIdx.x;
    const int t = threadIdx.x;

    if (b < 256) {
        __shared__ float crow[8][128];
        const int cgrp = b >> 4;
        const int kc   = b & 15;
        const int cell = t >> 6;
        const int hq   = t & 63;
        const int h0   = hq * 4;
        const int c    = cgrp * 8 + cell;

        #pragma unroll
        for (int p = 0; p < 2; ++p) {
            const int idx = p * 512 + t;
            const int lc  = idx >> 7;
            const int kk  = idx & 127;
            if (kk < 125)
                crow[lc][kk] = ctrl[(size_t)(cgrp * 8 + lc) * G_GENES + kc * 125 + kk];
        }
        __syncthreads();

        float4 s = {0.f, 0.f, 0.f, 0.f};
        const float* wbase = ce_w1 + (size_t)(kc * 125) * H_DIM + h0;
        #pragma unroll 5
        for (int k = 0; k < 125; ++k) {
            const float crv = crow[cell][k];
            const float4 wv = *(const float4*)(wbase + (size_t)k * H_DIM);
            s.x = fmaf(crv, wv.x, s.x);
            s.y = fmaf(crv, wv.y, s.y);
            s.z = fmaf(crv, wv.z, s.z);
            s.w = fmaf(crv, wv.w, s.w);
        }
        *(float4*)&hidpart[((size_t)kc * C_CELLS + c) * H_DIM + h0] = s;
    } else if (b < 272) {
        const int n  = (b - 256) * 16 + (t >> 5);
        const int k0 = (t & 31) * 8;
        float v[8];
        #pragma unroll
        for (int j = 0; j < 8; ++j) v[j] = g_w2[(size_t)(k0 + j) * H_DIM + n];
        U8 u;
        u.u[0] = pk2(v[0], v[1]); u.u[1] = pk2(v[2], v[3]);
        u.u[2] = pk2(v[4], v[5]); u.u[3] = pk2(v[6], v[7]);
        *(uint4*)&w2abt[(size_t)n * H_DIM + k0] = u.v;
    } else if (b < 288) {
        const int hr = (b - 272) * 16 + (t >> 5);
        const int j0 = (t & 31) * 8;
        const float* src = g_w2 + (size_t)(H_DIM + hr) * H_DIM + j0;
        float4 f0 = *(const float4*)src;
        float4 f1 = *(const float4*)(src + 4);
        U8 u;
        u.u[0] = pk2(f0.x, f0.y); u.u[1] = pk2(f0.z, f0.w);
        u.u[2] = pk2(f1.x, f1.y); u.u[3] = pk2(f1.z, f1.w);
        *(uint4*)&w2bb[(size_t)hr * H_DIM + j0] = u.v;
    } else {
        const int gq = b - 288;
        const int half = t >> 8;
        const int h = t & 255;
        const int gA = gq * 4 + half * 2;
        const int gB = gA + 1;
        const int iA = gidx[gA];
        const int iB = gidx[gB];

        const float b1   = g_b1[h];
        const float w129 = g_w1[(size_t)129 * H_DIM + h];
        const float w130 = g_w1[(size_t)130 * H_DIM + h];
        float bvA = b1 + 128.0f * w130 + shiftv[iA] * w129;
        float bvB = b1 + 128.0f * w130 + shiftv[iB] * w129;
        #pragma unroll 8
        for (int e = 0; e < CE_DIM; ++e) {
            const float wv = g_w1[(size_t)(65 + e) * H_DIM + h];
            bvA = fmaf(gtab[(size_t)iA * CE_DIM + e], wv, bvA);
            bvB = fmaf(gtab[(size_t)iB * CE_DIM + e], wv, bvB);
        }
        Bvg[(size_t)gA * H_DIM + h] = bvA;
        Bvg[(size_t)gB * H_DIM + h] = bvB;
    }
}

// ---------------------------------------------------------------------------
// K_fin: 128 blocks x 256 thr (R13 version)
// ---------------------------------------------------------------------------
__global__ __launch_bounds__(256) void k_fin(
    const float* __restrict__ hidpart, const float* __restrict__ ce_b1,
    const float* __restrict__ ce_w2, const float* __restrict__ ce_b2,
    const float* __restrict__ g_w1, unsigned short* __restrict__ Atcbf)
{
    __shared__ float hid[H_DIM];
    __shared__ float celp[4 * CE_DIM];
    __shared__ float cel[CE_DIM];
    const int c = blockIdx.x;
    const int t = threadIdx.x;

    float s = ce_b1[t];
    #pragma unroll
    for (int kc = 0; kc < 16; ++kc)
        s += hidpart[((size_t)kc * C_CELLS + c) * H_DIM + t];
    hid[t] = eluf(s);
    __syncthreads();

    {
        const int e = t & 63, q4 = t >> 6;
        float cp = 0.f;
        #pragma unroll 8
        for (int hh = 0; hh < 64; ++hh)
            cp = fmaf(hid[q4 * 64 + hh], ce_w2[(size_t)(q4 * 64 + hh) * CE_DIM + e], cp);
        celp[q4 * CE_DIM + e] = cp;
    }
    __syncthreads();
    if (t < CE_DIM)
        cel[t] = ce_b2[t] + celp[t] + celp[CE_DIM + t] + celp[2 * CE_DIM + t] + celp[3 * CE_DIM + t];
    __syncthreads();

    float a = 0.f;
    #pragma unroll 8
    for (int e = 0; e < CE_DIM; ++e) a = fmaf(cel[e], g_w1[(size_t)(1 + e) * H_DIM + t], a);
    Atcbf[(size_t)c * H_DIM + t] = f2bf(a);
}

// ---------------------------------------------------------------------------
// K_main: R16 form (equal-best, 111.3 us) + ONE change: s_setprio(1) around
// the MFMA loop (T5). Mechanism: 2 co-resident blocks/CU sit at different
// phases; boosting the MFMA-phase wave's priority keeps the matrix pipe fed
// while the other block issues VALU/VMEM. Zero register/LDS cost.
// FROZEN otherwise: phase order load-bearing (R15); no VMEM near the MFMA
// loop — 64 VGPR + 64 AGPR is exactly the 128-reg/4-wave boundary
// (R11/R12/R14 all spilled). Occupancy register-capped at 16 waves/CU.
// ---------------------------------------------------------------------------
__global__ __launch_bounds__(512, 4) void k_main(
    const float* __restrict__ ctrl, const int* __restrict__ gidx,
    const float* __restrict__ g_w1, const float* __restrict__ g_b2,
    const float* __restrict__ g_w3, const unsigned short* __restrict__ Atcbf,
    const float* __restrict__ Bvg, const unsigned short* __restrict__ w2abt,
    const unsigned short* __restrict__ w2bb, float* __restrict__ out)
{
    __shared__ __align__(16) unsigned short x1t[C_CELLS * LDAe];  // 66560 B
    __shared__ __align__(16) float scratch[8 * 258];              // pp -> red2
    __shared__ float pvec[H_DIM];
    __shared__ float qa[H_DIM];
    __shared__ float qb[H_DIM];
    __shared__ float b2l[H_DIM];
    __shared__ float w3v[H_DIM];

    const int g = blockIdx.x;
    const int t = threadIdx.x;
    const int idx = gidx[g];

    const int lane = t & 63;
    const int w    = t >> 6;
    const int quad = lane >> 4;
    const int nlo  = lane & 15;
    const int wm   = w >> 2;
    const int wn   = w & 3;

    // ---- prefetches (all independent) ----
    const int ho = t & 31, cgrp = t >> 5;
    const int h0 = ho * 8;
    uint4 A[8];                    // 8 rows x 8 bf16 Atc values (32 VGPRs)
    #pragma unroll
    for (int i = 0; i < 8; ++i)
        A[i] = *(const uint4*)(Atcbf + (size_t)(cgrp * 8 + i) * H_DIM + h0);
    float4 bv0 = *(const float4*)(Bvg + (size_t)g * H_DIM + h0);
    float4 bv1 = *(const float4*)(Bvg + (size_t)g * H_DIM + h0 + 4);
    float4 wv0 = *(const float4*)(g_w1 + h0);
    float4 wv1 = *(const float4*)(g_w1 + h0 + 4);

    const unsigned short* bbase = w2abt + (size_t)(wn * 64 + nlo) * H_DIM + quad * 8;
    short8 bcur[4];
    #pragma unroll
    for (int nt = 0; nt < 4; ++nt)
        bcur[nt] = *(const short8*)(bbase + (size_t)nt * 16 * H_DIM);

    // ctrl column values for this cgrp: lanes 0-7 of each half-wave load,
    // consumers pick them up via __shfl (no cc[] LDS, no B0).
    float ccl = 0.f;
    if ((lane & 31) < 8)
        ccl = ctrl[(size_t)(cgrp * 8 + (lane & 31)) * G_GENES + idx];

    if (t < H_DIM) {
        w3v[t] = g_w3[t];      // read after B3 only -> B1 covers visibility
        b2l[t] = g_b2[t];
    }

    {   // ---- x1 build (+ register p-partials) ----
        float s[8];
        #pragma unroll
        for (int j = 0; j < 8; ++j) s[j] = 0.f;
        #pragma unroll
        for (int i = 0; i < 8; ++i) {
            const int c = cgrp * 8 + i;
            const float ccv = __shfl(ccl, (lane & 32) + i);
            float v0 = eluf(fmaf(ccv, wv0.x, bflo(A[i].x) + bv0.x));
            float v1 = eluf(fmaf(ccv, wv0.y, bfhi(A[i].x) + bv0.y));
            float v2 = eluf(fmaf(ccv, wv0.z, bflo(A[i].y) + bv0.z));
            float v3 = eluf(fmaf(ccv, wv0.w, bfhi(A[i].y) + bv0.w));
            float v4 = eluf(fmaf(ccv, wv1.x, bflo(A[i].z) + bv1.x));
            float v5 = eluf(fmaf(ccv, wv1.y, bfhi(A[i].z) + bv1.y));
            float v6 = eluf(fmaf(ccv, wv1.z, bflo(A[i].w) + bv1.z));
            float v7 = eluf(fmaf(ccv, wv1.w, bfhi(A[i].w) + bv1.w));
            s[0] += v0; s[1] += v1; s[2] += v2; s[3] += v3;
            s[4] += v4; s[5] += v5; s[6] += v6; s[7] += v7;
            uint4 pk;
            pk.x = pk2(v0, v1); pk.y = pk2(v2, v3);
            pk.z = pk2(v4, v5); pk.w = pk2(v6, v7);
            *(uint4*)&x1t[c * LDAe + h0] = pk;
        }
        #pragma unroll
        for (int j = 0; j < 8; ++j) s[j] += __shfl_xor(s[j], 32);
        if (lane < 32) {
            float4 p0 = {s[0], s[1], s[2], s[3]};
            float4 p1 = {s[4], s[5], s[6], s[7]};
            *(float4*)&scratch[w * 258 + h0] = p0;
            *(float4*)&scratch[w * 258 + h0 + 4] = p1;
        }
    }
    __syncthreads();   // B1: x1t + pp complete

    // ---- MFMA: 4mt x 4nt, K=256 in 8 steps, B-frags double-buffered ----
    floatx4 acc[4][4];
    #pragma unroll
    for (int mt = 0; mt < 4; ++mt)
        #pragma unroll
        for (int nt = 0; nt < 4; ++nt)
            acc[mt][nt] = (floatx4){0.f, 0.f, 0.f, 0.f};

    const unsigned short* abase = &x1t[(wm * 64 + nlo) * LDAe + quad * 8];

    __builtin_amdgcn_s_setprio(1);   // T5: favor MFMA-phase waves on the CU
    #pragma unroll
    for (int kt = 0; kt < 8; ++kt) {
        short8 af[4];
        #pragma unroll
        for (int mt = 0; mt < 4; ++mt)
            af[mt] = *(const short8*)(abase + mt * 16 * LDAe + kt * 32);
        short8 bnx[4];
        if (kt < 7) {
            #pragma unroll
            for (int nt = 0; nt < 4; ++nt)
                bnx[nt] = *(const short8*)(bbase + (size_t)nt * 16 * H_DIM + (kt + 1) * 32);
        }
        #pragma unroll
        for (int nt = 0; nt < 4; ++nt)
            #pragma unroll
            for (int mt = 0; mt < 4; ++mt)
                acc[mt][nt] = __builtin_amdgcn_mfma_f32_16x16x32_bf16(af[mt], bcur[nt], acc[mt][nt], 0, 0, 0);
        if (kt < 7) {
            #pragma unroll
            for (int nt = 0; nt < 4; ++nt) bcur[nt] = bnx[nt];
        }
    }
    __builtin_amdgcn_s_setprio(0);

    // ---- p-reduce into pvec ----
    if (t < H_DIM) {
        float ps = 0.f;
        #pragma unroll
        for (int w2 = 0; w2 < 8; ++w2) ps += scratch[w2 * 258 + t];
        pvec[t] = ps * (1.0f / 128.0f);
    }
    __syncthreads();   // B2: pvec ready

    // ---- q halves: qa (h<128), qb (h>=128); scalar loads (reg-safe) ----
    {
        const int j = t & 255, hf = t >> 8;
        const unsigned short* wp = w2bb + (size_t)(hf * 128) * H_DIM + j;
        const float* pv = pvec + hf * 128;
        float q0 = 0.f, q1 = 0.f, q2 = 0.f, q3 = 0.f;
        #pragma unroll 8
        for (int h = 0; h < 128; h += 4) {
            q0 = fmaf(pv[h + 0], bflo((unsigned)wp[(size_t)(h + 0) * H_DIM] << 16), q0);
            q1 = fmaf(pv[h + 1], bflo((unsigned)wp[(size_t)(h + 1) * H_DIM] << 16), q1);
            q2 = fmaf(pv[h + 2], bflo((unsigned)wp[(size_t)(h + 2) * H_DIM] << 16), q2);
            q3 = fmaf(pv[h + 3], bflo((unsigned)wp[(size_t)(h + 3) * H_DIM] << 16), q3);
        }
        const float qp = (q0 + q1) + (q2 + q3);
        if (hf) qb[j] = qp; else qa[j] = qp;
    }
    __syncthreads();   // B3: qa/qb ready

    // ---- epilogue: logit partials (C/D: col=lane&15, row=quad*4+reg) ----
    float* red2 = scratch;
    float qj[4], w3j[4];
    #pragma unroll
    for (int nt = 0; nt < 4; ++nt) {
        const int j = wn * 64 + nt * 16 + nlo;
        qj[nt] = qa[j] + qb[j] + b2l[j];
        w3j[nt] = w3v[j];
    }
    #pragma unroll
    for (int mt = 0; mt < 4; ++mt) {
        #pragma unroll
        for (int reg = 0; reg < 4; ++reg) {
            float part = 0.f;
            #pragma unroll
            for (int nt = 0; nt < 4; ++nt)
                part = fmaf(eluf(acc[mt][nt][reg] + qj[nt]), w3j[nt], part);
            part += __shfl_xor(part, 1);
            part += __shfl_xor(part, 2);
            part += __shfl_xor(part, 4);
            part += __shfl_xor(part, 8);
            if (nlo == 0)
                red2[(wm * 64 + mt * 16 + quad * 4 + reg) * 5 + wn] = part;
        }
    }
    __syncthreads();   // B4: red2 complete

    // ---- softmax: wave 0 only, 2 cells/lane ----
    if (t < 64) {
        const float s0 = red2[t * 5 + 0] + red2[t * 5 + 1]
                       + red2[t * 5 + 2] + red2[t * 5 + 3];
        const float s1 = red2[(t + 64) * 5 + 0] + red2[(t + 64) * 5 + 1]
                       + red2[(t + 64) * 5 + 2] + red2[(t + 64) * 5 + 3];
        const float e0 = __expf(fminf(s0, 80.f));
        const float e1 = __expf(fminf(s1, 80.f));
        float S = e0 + e1;
        #pragma unroll
        for (int off = 1; off < 64; off <<= 1) S += __shfl_xor(S, off);
        const float inv = 1.0f / S;
        out[(size_t)t * G_GENES + g] = e0 * inv;
        out[(size_t)(t + 64) * G_GENES + g] = e1 * inv;
    }
}

// ---------------------------------------------------------------------------
extern "C" void kernel_launch(void* const* d_in, const int* in_sizes, int n_in,
                              void* d_out, int out_size, void* d_ws, size_t ws_size,
                              hipStream_t stream) {
    const float* ctrl   = (const float*)d_in[0];
    const float* shiftv = (const float*)d_in[1];
    const int*   gidx   = (const int*)d_in[2];
    const float* ce_w1  = (const float*)d_in[3];
    const float* ce_b1  = (const float*)d_in[4];
    const float* ce_w2  = (const float*)d_in[5];
    const float* ce_b2  = (const float*)d_in[6];
    const float* gtab   = (const float*)d_in[7];
    const float* g_w1   = (const float*)d_in[8];
    const float* g_b1   = (const float*)d_in[9];
    const float* g_w2   = (const float*)d_in[10];
    const float* g_b2   = (const float*)d_in[11];
    const float* g_w3   = (const float*)d_in[12];
    // g_b3 and the p2@w3b term are per-gene constants: cancel in softmax.

    // workspace: Atcbf 128K | w2abt 128K | w2bb 128K | Bvg 2M | hidpart 2M
    char* ws = (char*)d_ws;
    unsigned short* Atcbf = (unsigned short*)(ws);
    unsigned short* w2abt = (unsigned short*)(ws + 128 * 1024);
    unsigned short* w2bb  = (unsigned short*)(ws + 256 * 1024);
    float* Bvg            = (float*)(ws + 384 * 1024);
    float* hidpart        = (float*)(ws + 384 * 1024 + (size_t)G_GENES * H_DIM * 4);
    float* out            = (float*)d_out;

    k_g1<<<788, 512, 0, stream>>>(
        ctrl, ce_w1, g_w1, g_b1, shiftv, gidx, gtab, g_w2, hidpart, w2abt, w2bb, Bvg);
    k_fin<<<C_CELLS, 256, 0, stream>>>(hidpart, ce_b1, ce_w2, ce_b2, g_w1, Atcbf);
    k_main<<<G_GENES, 512, 0, stream>>>(ctrl, gidx, g_w1, g_b2, g_w3,
                                        Atcbf, Bvg, w2abt, w2bb, out);
}